// Round 8
// baseline (860.341 us; speedup 1.0000x reference)
//
#include <hip/hip_runtime.h>
#include <hip/hip_bf16.h>

// B=32, C=256, H=36, W=64, n=4096.  P = H*W = 2304.  NCOL = B*C = 8192.
#define P_HW   2304
#define NG     4096
#define NCOL   8192
#define KDIM   P_HW
#define NT     72          // K-tiles of 32: 2304/32

typedef __bf16 bf16x8 __attribute__((ext_vector_type(8)));
typedef float  f32x4  __attribute__((ext_vector_type(4)));

__device__ __forceinline__ unsigned short f2bf(float f) {
    union { float f; unsigned int u; } x; x.f = f;
    unsigned int r = x.u + 0x7FFFu + ((x.u >> 16) & 1u);   // RNE
    return (unsigned short)(r >> 16);
}

// ---------------------------------------------------------------------------
// Prep: cast-only now (masks are generated on the fly inside the GEMM).
// ---------------------------------------------------------------------------
__global__ __launch_bounds__(256) void prep_kernel(
    const float* __restrict__ feat,
    unsigned short* __restrict__ F) {
    const size_t i = ((size_t)blockIdx.x * 256 + threadIdx.x) * 8;
    const float4 v0 = *(const float4*)(feat + i);
    const float4 v1 = *(const float4*)(feat + i + 4);
    union { unsigned short s[8]; uint4 q; } o;
    o.s[0] = f2bf(v0.x); o.s[1] = f2bf(v0.y); o.s[2] = f2bf(v0.z); o.s[3] = f2bf(v0.w);
    o.s[4] = f2bf(v1.x); o.s[5] = f2bf(v1.y); o.s[6] = f2bf(v1.z); o.s[7] = f2bf(v1.w);
    *(uint4*)(F + i) = o.q;
}

// ---------------------------------------------------------------------------
// GEMM v8 = v4 free-run core + ON-THE-FLY A (Gaussian masks) into LDS.
// R7 post-mortem: 4 different schedules all pin at 37-43% MfmaUtil; FETCH
// 132-143 MB vs 56.6 MB input = 2.3x HBM re-fetch (A-panels re-fetched per
// XCD).  A is analytic -> generate the A-tile per block directly into the
// SAME swizzled LDS slots (~192 VALU cyc/CU-tile on an 84%-idle pipe),
// killing A staging VMEM + A HBM fetch + G materialization + prep's mask
// branch.  B keeps proven gload_lds depth-3 ring (vmcnt(4): 2 loads/tile).
// A is depth-1 ds_writes, drained by lgkmcnt(0) folded into the per-tile
// end wait.  Swizzle/reads/epilogue byte-identical to v4 (proven).
// ---------------------------------------------------------------------------
__device__ __forceinline__ void async16(const void* g, void* l) {
    __builtin_amdgcn_global_load_lds(
        (__attribute__((address_space(1))) void*)(unsigned long long)g,
        (__attribute__((address_space(3))) void*)(unsigned int)(unsigned long long)l,
        16, 0, 0);
}

__global__ __launch_bounds__(512, 2) void gemm_fused(
    const unsigned short* __restrict__ F,   // [NCOL][K] bf16
    const float* __restrict__ mu,           // [NG][2]
    const float* __restrict__ logsx,
    const float* __restrict__ logsy,
    const float* __restrict__ rho,
    const float* __restrict__ weight,       // [NG][256] fp32
    float* __restrict__ out)                // [32][NG] fp32
{
    // 4 ring buffers; each: A[256][32] + B[256][32] bf16.
    // LDS slot (r, cp) holds global chunk c = cp ^ ((r>>1)&3)  [XOR swizzle].
    __shared__ __align__(16) unsigned short lds[4 * 16384];

    const int tid  = threadIdx.x;            // 0..511
    const int lane = tid & 63;
    const int wid  = tid >> 6;               // 0..7
    const int wr   = wid >> 2;               // 0..1  (M half: 128 rows)
    const int wc   = wid & 3;                // 0..3  (N quarter: 64 cols)
    const int quad = lane >> 4, m = lane & 15;

    const int rowBase = blockIdx.y * 256;    // over NG
    const int colBase = blockIdx.x * 256;    // over NCOL (= b*256)

    // Staging geometry (v4): thread t, round i -> r = i*128 + (t>>2),
    // global chunk c = (t&3) ^ ((t>>3)&3)  [i-invariant].
    const int rA = tid >> 2;
    const int cA = (tid & 3) ^ ((tid >> 3) & 3);
    const unsigned short* pB = F + (size_t)(colBase + rA) * KDIM + cA * 8;

    // Per-block A-row params: this thread owns rows rA0 = tid>>2 and +128.
    float mux[2], muy[2], isx[2], isy[2], rr[2], inv[2];
#pragma unroll
    for (int i = 0; i < 2; ++i) {
        const int n = rowBase + (tid >> 2) + i * 128;
        mux[i] = mu[2 * n]; muy[i] = mu[2 * n + 1];
        isx[i] = 1.0f / (__expf(logsx[n]) + 1e-6f);
        isy[i] = 1.0f / (__expf(logsy[n]) + 1e-6f);
        const float r = tanhf(rho[n]);
        rr[i]  = r;
        inv[i] = 1.0f / (2.0f * (1.0f - r * r + 1e-6f));
    }

    // Generate A-tile KT (k0 = KT*32) into LDS at DST (A-region base).
    // h = p>>6 is tile-constant (32 k's never cross a W=64 row boundary);
    // w-col = (k0&32) + cA*8 + j.  Formula bit-identical to old prep.
#define GEN_A(KT, DST)                                                     \
    {                                                                      \
        const int   k0 = (KT) * 32;                                        \
        const float Yt = -1.0f + (float)(k0 >> 6) * (2.0f / 35.0f);        \
        const int   wb = (k0 & 32) + cA * 8;                               \
        _Pragma("unroll")                                                  \
        for (int i = 0; i < 2; ++i) {                                      \
            const float yc = (Yt - muy[i]) * isy[i];                       \
            union { unsigned short s[8]; uint4 q; } o;                     \
            _Pragma("unroll")                                              \
            for (int j = 0; j < 8; ++j) {                                  \
                const float X  = -1.0f + (float)(wb + j) * (2.0f / 63.0f); \
                const float xc = (X - mux[i]) * isx[i];                    \
                const float A  = xc * xc + yc * yc                         \
                                 - 2.0f * rr[i] * xc * yc;                 \
                o.s[j] = f2bf(__expf(-A * inv[i]));                        \
            }                                                              \
            *(uint4*)&lds[(DST) + i * 4096 + tid * 8] = o.q;               \
        }                                                                  \
    }

    // ds_read: row = band + m (band mult of 16), chunk cp = quad ^ ((m>>1)&3)
    const int sw   = (quad ^ ((m >> 1) & 3)) * 8;
    const int aoff = (wr * 128 + m) * 32 + sw;
    const int boff = (wc * 64  + m) * 32 + sw;

    f32x4 acc[8][4];
#pragma unroll
    for (int i = 0; i < 8; ++i)
#pragma unroll
        for (int j = 0; j < 4; ++j)
            acc[i][j] = (f32x4){0.f, 0.f, 0.f, 0.f};

    // Prologue: A tile0 via mask-gen; B tiles 0,1,2 staged (6 gloads).
    GEN_A(0, 0);
#pragma unroll
    for (int t2 = 0; t2 < 3; ++t2) {
        async16(pB + t2 * 32,              &lds[t2 * 16384 + 8192  + tid * 8]);
        async16(pB + t2 * 32 + 128 * KDIM, &lds[t2 * 16384 + 12288 + tid * 8]);
    }
    asm volatile("s_waitcnt vmcnt(4) lgkmcnt(0)" ::: "memory");
    __builtin_amdgcn_s_barrier();
    asm volatile("" ::: "memory");

    // Main loop: tile t from buf t&3.  A for t+1 generated depth-1 into
    // (t+1)&3 (that A-region was consumed at tile t-3).  B for t+3 staged
    // into (t+3)&3 (consumed at t-1).  vmcnt(4) leaves B t+2,t+3 in flight;
    // lgkmcnt(0) drains the A ds_writes before the publishing barrier.
    for (int tt = 0; tt < NT; tt += 4) {
#pragma unroll
        for (int u = 0; u < 4; ++u) {
            const int t    = tt + u;
            const int bo   = u * 16384;              // static
            const int wAbo = ((u + 1) & 3) * 16384;  // static
            const int wBbo = ((u + 3) & 3) * 16384;  // static
            int wA = t + 1; if (wA >= NT) wA -= NT;  // wrap: garbage into
            int wB = t + 3; if (wB >= NT) wB -= NT;  // consumed regions
            const unsigned short* pBw = pB + wB * 32;

            // issue B staging first (max lead), then A mask-gen (VALU work
            // the compiler spreads into MFMA gaps)
            async16(pBw,              &lds[wBbo + 8192  + tid * 8]);
            async16(pBw + 128 * KDIM, &lds[wBbo + 12288 + tid * 8]);
            GEN_A(wA, wAbo);

            // 12 ds_reads + 32 MFMA; compiler interleaves via counted lgkmcnt
            bf16x8 a[8], b[4];
#pragma unroll
            for (int j = 0; j < 4; ++j)
                b[j] = *(const bf16x8*)&lds[bo + 8192 + boff + j * 512];
#pragma unroll
            for (int i = 0; i < 8; ++i)
                a[i] = *(const bf16x8*)&lds[bo + aoff + i * 512];

            __builtin_amdgcn_s_setprio(1);
#pragma unroll
            for (int i = 0; i < 8; ++i)
#pragma unroll
                for (int j = 0; j < 4; ++j)
                    acc[i][j] = __builtin_amdgcn_mfma_f32_16x16x32_bf16(a[i], b[j], acc[i][j], 0, 0, 0);
            __builtin_amdgcn_s_setprio(0);

            asm volatile("s_waitcnt vmcnt(4) lgkmcnt(0)" ::: "memory");
            __builtin_amdgcn_s_barrier();
            asm volatile("" ::: "memory");
        }
    }

    // Drain wrapped garbage (B gloads + A writes) before reusing LDS.
    asm volatile("s_waitcnt vmcnt(0) lgkmcnt(0)" ::: "memory");
    __syncthreads();

    // Epilogue: out[b][n] = sum_c pooled[n][b*256+c] * weight[n][c].
    float* red = (float*)lds;                // [4 wc][256 n_local]
    const int cwbase = wc * 64 + m;
#pragma unroll
    for (int i = 0; i < 8; ++i) {
#pragma unroll
        for (int reg = 0; reg < 4; ++reg) {
            const int nloc = wr * 128 + i * 16 + quad * 4 + reg;
            const float* wrow = weight + (size_t)(rowBase + nloc) * 256 + cwbase;
            float s = 0.f;
#pragma unroll
            for (int j = 0; j < 4; ++j)
                s += acc[i][j][reg] * wrow[j * 16];
            s += __shfl_xor(s, 1);
            s += __shfl_xor(s, 2);
            s += __shfl_xor(s, 4);
            s += __shfl_xor(s, 8);
            if (m == 0)
                red[wc * 256 + nloc] = s;
        }
    }
    __syncthreads();
    if (tid < 256) {
        const float s = red[tid] + red[256 + tid] + red[512 + tid] + red[768 + tid];
        out[(size_t)blockIdx.x * NG + rowBase + tid] = s;
    }
}

// ---------------------------------------------------------------------------
extern "C" void kernel_launch(void* const* d_in, const int* in_sizes, int n_in,
                              void* d_out, int out_size, void* d_ws, size_t ws_size,
                              hipStream_t stream) {
    const float* feat   = (const float*)d_in[0];
    const float* mu     = (const float*)d_in[1];
    const float* logsx  = (const float*)d_in[2];
    const float* logsy  = (const float*)d_in[3];
    const float* rho    = (const float*)d_in[4];
    const float* weight = (const float*)d_in[5];
    float* out = (float*)d_out;

    unsigned short* Fbuf = (unsigned short*)d_ws;   // 8192*2304*2 B (only F now)

    hipLaunchKernelGGL(prep_kernel, dim3(9216), dim3(256), 0, stream, feat, Fbuf);

    hipLaunchKernelGGL(gemm_fused, dim3(NCOL / 256, NG / 256), dim3(512), 0, stream,
                       Fbuf, mu, logsx, logsy, rho, weight, out);
}